// Round 8
// baseline (212.716 us; speedup 1.0000x reference)
//
#include <hip/hip_runtime.h>
#include <cstdint>

// Problem constants
#define LN_EPS 1e-5f

typedef _Float16 f16;
typedef _Float16 half4_t __attribute__((ext_vector_type(4)));
typedef _Float16 half8_t __attribute__((ext_vector_type(8)));
typedef __fp16 fp16v2 __attribute__((ext_vector_type(2)));
typedef float f32x4 __attribute__((ext_vector_type(4)));

// async global->LDS, 16B per lane; LDS dest = wave-uniform base + lane*16
__device__ __forceinline__ void gl_lds16(const void* g, void* l) {
    __builtin_amdgcn_global_load_lds(
        (__attribute__((address_space(1))) void*)(uintptr_t)g,
        (__attribute__((address_space(3))) void*)(uint32_t)(uintptr_t)l,
        16, 0, 0);
}

// pack 4 floats -> 4 f16 via v_cvt_pkrtz
__device__ __forceinline__ half4_t pack4(float a, float b, float c, float d) {
    fp16v2 lo = __builtin_amdgcn_cvt_pkrtz(a, b);
    fp16v2 hi = __builtin_amdgcn_cvt_pkrtz(c, d);
    half4_t r;
    r[0] = (f16)lo[0]; r[1] = (f16)lo[1]; r[2] = (f16)hi[0]; r[3] = (f16)hi[1];
    return r;
}

// ---------------------------------------------------------------- cast weights + inputs
// W1 (1536x512), W2 (512x512), and X = [query|key_in|value] (3 x 8192x512) -> f16.
// R11: grid-stride (4 reps/thread) -> 3328 blocks.
__global__ void k_cast(const float* __restrict__ W1f, const float* __restrict__ W2f,
                       const float* __restrict__ Xq, const float* __restrict__ Xk,
                       const float* __restrict__ Xv,
                       f16* __restrict__ W1h, f16* __restrict__ W2h,
                       f16* __restrict__ Xh) {
    int t0 = blockIdx.x * blockDim.x + threadIdx.x;   // 3328*256 = 851,968 threads
    #pragma unroll
    for (int rep = 0; rep < 4; ++rep) {
        int t = t0 + rep * 851968;                    // 4 reps = 3,407,872 float4
        const float4* src;
        half4_t* dst;
        int idx;
        if (t < 196608)      { src = (const float4*)W1f; dst = (half4_t*)W1h; idx = t; }
        else if (t < 262144) { src = (const float4*)W2f; dst = (half4_t*)W2h; idx = t - 196608; }
        else {
            int u = t - 262144;               // 0 .. 3,145,727
            int s = u >> 20;                  // input selector (2^20 float4 per input)
            idx = u & 1048575;
            src = (s == 0) ? (const float4*)Xq : ((s == 1) ? (const float4*)Xk : (const float4*)Xv);
            dst = (half4_t*)(Xh + (size_t)s * 4194304);
        }
        float4 v = src[idx];
        dst[idx] = pack4(v.x, v.y, v.z, v.w);
    }
}

// ---------------------------------------------------------------- in-projection (+ fused LayerNorm for K,V; V written transposed)
// C = X @ W^T + b ; X f16 (per-section 8192x512), W f16.
// R10 K-loop: triple-buffered LDS + counted vmcnt(4) + raw s_barrier.
// R14: unroll-by-3 (compile-time slot pointers -> LICM'd LDS addressing).
// R13: flat grid 768 with XCD remap. Epilogue: fused Q-scale / LN; K chunk-major;
// V transposed straight to Vtg. Q pre-scaled by beta*log2(e).
__global__ __launch_bounds__(256) void k_inproj(
    const f16* __restrict__ Xh, const f16* __restrict__ W1,
    const float* __restrict__ bias, const float* __restrict__ scaling,
    const float* __restrict__ pnw, const float* __restrict__ pnb,
    f16* __restrict__ Qg, f16* __restrict__ Kg, f16* __restrict__ Vtg)
{
    __shared__ __align__(16) char pool[49152];   // 3 slots x (A 8KB + B 8KB); Ep 32KB aliases

    const int tid = threadIdx.x;
    const int bid = blockIdx.x;                  // 768 blocks
    const int jj = bid >> 3;
    const int m0 = ((bid & 7) * 8 + (jj & 7)) * 128;   // m-block [0,64)*128
    const int f0 = (jj >> 3) * 128;                    // f-block [0,12)*128
    const int sec = f0 >> 9;
    const f16* X = Xh + (size_t)sec * 4194304;
    f16* Ob = (sec == 0) ? Qg : Kg;              // sec==2 uses Vtg path

    const int wid = tid >> 6, ln = tid & 63, l15 = ln & 15, quad = ln >> 4;
    const int wm = wid >> 1, wn = wid & 1;
    const int srow = ln >> 2, sco = (ln & 3) * 8;

    f16* A0 = (f16*)(pool);          f16* B0 = (f16*)(pool + 8192);
    f16* A1 = (f16*)(pool + 16384);  f16* B1 = (f16*)(pool + 24576);
    f16* A2 = (f16*)(pool + 32768);  f16* B2 = (f16*)(pool + 40960);

    f32x4 z4 = {0.f, 0.f, 0.f, 0.f};
    f32x4 acc[4][4];
    #pragma unroll
    for (int i = 0; i < 4; ++i)
        #pragma unroll
        for (int j = 0; j < 4; ++j) acc[i][j] = z4;

    // per-tile staging: 4 gl_lds16 per wave (2 for B, 2 for A)
    auto issue = [&](int kt, f16* As, f16* Bs) {
        const int k0 = kt * 32;
        #pragma unroll
        for (int i = 0; i < 2; ++i) {
            int row = wid * 32 + i * 16 + srow;
            gl_lds16(W1 + (size_t)(f0 + row) * 512 + k0 + sco,
                     Bs + (wid * 32 + i * 16) * 32);
            gl_lds16(X + (size_t)(m0 + row) * 512 + k0 + sco,
                     As + (wid * 32 + i * 16) * 32);
        }
    };
    issue(0, A0, B0);
    issue(1, A1, B1);

    auto bodyk = [&](int kt, const f16* As, const f16* Bs, f16* Ans, f16* Bns) {
        if (kt < 15) asm volatile("s_waitcnt vmcnt(4)" ::: "memory");
        else         asm volatile("s_waitcnt vmcnt(0)" ::: "memory");
        __builtin_amdgcn_s_barrier();

        if (kt < 14) issue(kt + 2, Ans, Bns);

        half8_t a[4], b[4];
        #pragma unroll
        for (int i = 0; i < 4; ++i)
            a[i] = *(const half8_t*)(As + (wm * 64 + i * 16 + l15) * 32 + quad * 8);
        #pragma unroll
        for (int j = 0; j < 4; ++j)
            b[j] = *(const half8_t*)(Bs + (wn * 64 + j * 16 + l15) * 32 + quad * 8);
        __builtin_amdgcn_s_setprio(1);
        #pragma unroll
        for (int i = 0; i < 4; ++i)
            #pragma unroll
            for (int j = 0; j < 4; ++j)
                acc[i][j] = __builtin_amdgcn_mfma_f32_16x16x32_f16(b[j], a[i], acc[i][j], 0, 0, 0);
        __builtin_amdgcn_s_setprio(0);
    };

    #pragma unroll 1
    for (int tt = 0; tt < 5; ++tt) {
        bodyk(tt * 3,     A0, B0, A2, B2);
        bodyk(tt * 3 + 1, A1, B1, A0, B0);
        bodyk(tt * 3 + 2, A2, B2, A1, B1);
    }
    bodyk(15, A0, B0, A2, B2);

    // ---- epilogue: bias (+Q-scale | +LN), LDS re-stage, coalesced output ----
    __syncthreads();                       // all waves done with staging slots
    f16* Ep = (f16*)pool;                  // [mloc 128][col 128], col fgrp XOR-swizzled

    // per-lane constants
    float sA = 0.f, sB = 0.f;              // Q scale for j<2 / j>=2 head
    float4 wA, wB, bA, bB;                 // LN params, d0 = (j&1)*16 + quad*4
    if (sec == 0) {
        int hbase = ((f0 & 511) >> 5) + wn * 2;
        sA = scaling[hbase] * 1.44269504f;
        sB = scaling[hbase + 1] * 1.44269504f;
    } else {
        wA = *(const float4*)(pnw + quad * 4);
        wB = *(const float4*)(pnw + 16 + quad * 4);
        bA = *(const float4*)(pnb + quad * 4);
        bB = *(const float4*)(pnb + 16 + quad * 4);
    }
    float4 bias4[4];
    #pragma unroll
    for (int j = 0; j < 4; ++j)
        bias4[j] = *(const float4*)(bias + f0 + wn * 64 + j * 16 + quad * 4);

    #pragma unroll
    for (int i = 0; i < 4; ++i) {
        float x[4][4];
        #pragma unroll
        for (int j = 0; j < 4; ++j) {
            x[j][0] = acc[i][j][0] + bias4[j].x;
            x[j][1] = acc[i][j][1] + bias4[j].y;
            x[j][2] = acc[i][j][2] + bias4[j].z;
            x[j][3] = acc[i][j][3] + bias4[j].w;
        }
        if (sec == 0) {
            #pragma unroll
            for (int j = 0; j < 4; ++j) {
                float sc = (j < 2) ? sA : sB;
                #pragma unroll
                for (int r = 0; r < 4; ++r) x[j][r] *= sc;
            }
        } else {
            // LN over the 32 features of each head: lane holds 8 (2 j x 4 r);
            // quad-reduce (shfl 16/32) completes the 32-feature sum.
            #pragma unroll
            for (int hp = 0; hp < 2; ++hp) {
                float s1 = 0.f, s2 = 0.f;
                #pragma unroll
                for (int jq = 0; jq < 2; ++jq) {
                    int j = hp * 2 + jq;
                    #pragma unroll
                    for (int r = 0; r < 4; ++r) { s1 += x[j][r]; s2 += x[j][r] * x[j][r]; }
                }
                s1 += __shfl_xor(s1, 16); s1 += __shfl_xor(s1, 32);
                s2 += __shfl_xor(s2, 16); s2 += __shfl_xor(s2, 32);
                float mu = s1 * (1.f / 32.f);
                float rs = rsqrtf(s2 * (1.f / 32.f) - mu * mu + LN_EPS);
                #pragma unroll
                for (int jq = 0; jq < 2; ++jq) {
                    int j = hp * 2 + jq;
                    const float4& wv = (j & 1) ? wB : wA;
                    const float4& bv = (j & 1) ? bB : bA;
                    x[j][0] = (x[j][0] - mu) * rs * wv.x + bv.x;
                    x[j][1] = (x[j][1] - mu) * rs * wv.y + bv.y;
                    x[j][2] = (x[j][2] - mu) * rs * wv.z + bv.z;
                    x[j][3] = (x[j][3] - mu) * rs * wv.w + bv.w;
                }
            }
        }
        int mloc = wm * 64 + i * 16 + l15;
        int key = (mloc >> 2) & 7;
        #pragma unroll
        for (int j = 0; j < 4; ++j) {
            int floc0 = wn * 64 + j * 16 + quad * 4;
            *(half4_t*)(Ep + mloc * 128 + (floc0 ^ (key << 3))) =
                pack4(x[j][0], x[j][1], x[j][2], x[j][3]);
        }
    }
    __syncthreads();

    if (sec < 2) {
        // read phase: thread owns fgrp (8 features); stores contiguous in l
        // (16 lanes x 16B = 256B runs). Q and K chunk-major T[g][c][len][8].
        int fgrp = (tid >> 6) * 4 + quad;       // 0..15
        int fs = (f0 & 511) + fgrp * 8;
        int hh = fs >> 5, cc = (fs >> 3) & 3;
        #pragma unroll
        for (int it = 0; it < 8; ++it) {
            int nb = it & 3, lblk = it >> 2;
            int L = lblk * 16 + l15;
            int mloc = nb + 4 * L;
            half8_t v = *(const half8_t*)(Ep + mloc * 128 + ((fgrp ^ (L & 7)) << 3));
            int gg = nb * 16 + hh;
            size_t l = (size_t)(m0 >> 2) + L;
            *(half8_t*)(Ob + (size_t)gg * 65536 + (size_t)cc * 16384 + l * 8) = v;
        }
    } else {
        // V: transpose-out straight to Vtg [g][seg][d=32][c'][8], c' = cs^(d&7).
        int seg = m0 >> 8;                      // (m0/128)>>1
        int csb = ((m0 >> 7) & 1) * 4;          // (m-block & 1)*4
        int hbase = (f0 & 511) >> 5;
        #pragma unroll
        for (int p = 0; p < 2; ++p) {
            int idx = tid * 2 + p;
            int g16 = idx >> 5, d = idx & 31;
            int nb = g16 >> 2, hhl = g16 & 3;
            int floc = hhl * 32 + d;
            size_t obase = (size_t)((nb * 16 + hbase + hhl) * 32 + seg) * 2048 + d * 64;
            #pragma unroll
            for (int cq = 0; cq < 4; ++cq) {
                half8_t hv;
                #pragma unroll
                for (int es = 0; es < 8; ++es) {
                    int mloc = nb + 4 * (cq * 8 + es);
                    hv[es] = Ep[mloc * 128 + (floc ^ (es << 3))];
                }
                int csx = (csb + cq) ^ (d & 7);
                *(half8_t*)(Vtg + obase + csx * 8) = hv;
            }
        }
    }
}

// ---------------------------------------------------------------- flash attention
// R14: R8 schedule (counted vmcnt(2), one barrier/tile, 3-buf) with the tile
// loop unrolled by 3 so every LDS base is a compile-time slot pointer (LICM'd),
// plus max3-fusable fmax trees. Schedule semantics identical to R8 (78.3us).
// LDS 40KB: K 3x4K @0 / V 3x4K @12288 / P 4x4K @24576 -> 4 blocks/CU.
__global__ __launch_bounds__(256, 4) void k_flash(
    const f16* __restrict__ Qg, const f16* __restrict__ Kg,
    const f16* __restrict__ Vtg, f16* __restrict__ Og)
{
    __shared__ __align__(16) char smem[40960];

    const int tid = threadIdx.x, wid = tid >> 6, ln = tid & 63;
    const int l15 = ln & 15, quad = ln >> 4, l8 = ln & 7;
    char* Pw = smem + 24576 + wid * 4096;
    const int g = blockIdx.x, h = g & 15, n = g >> 4;
    const int q0 = blockIdx.y * 128;

    // Q fragments: direct global->register. lane (l15,quad) holds
    // B[k = d = quad*8+j][n = q = wid*32 + i*16 + l15] (Qg chunk-major [g][c][l][8]).
    half8_t aq[2];
    #pragma unroll
    for (int i = 0; i < 2; ++i)
        aq[i] = *(const half8_t*)(Qg + (size_t)g * 65536 + (size_t)quad * 16384 +
                                  (size_t)(q0 + wid * 32 + i * 16 + l15) * 8);

    // prologue: issue K/V for tiles 0 and 1 (wave stages its c-chunk of each)
    const f16* kp = Kg + (size_t)g * 65536 + (size_t)wid * 16384;
    const f16* vp = Vtg + (size_t)(g * 32) * 2048 + wid * 512;
    gl_lds16(kp + (size_t)ln * 8, smem + wid * 1024);
    gl_lds16(vp + (size_t)ln * 8, smem + 12288 + wid * 1024);
    gl_lds16(kp + 512 + (size_t)ln * 8, smem + 4096 + wid * 1024);
    gl_lds16(vp + 2048 + (size_t)ln * 8, smem + 12288 + 4096 + wid * 1024);
    kp += 1024;   // now points at tile 2
    vp += 4096;

    // ones A-fragment: row m=0 is all 1 -> MFMA accumulates column sums of B
    half8_t onesf;
    {
        f16 o = (l15 == 0) ? (f16)1.0f : (f16)0.0f;
        #pragma unroll
        for (int j = 0; j < 8; ++j) onesf[j] = o;
    }

    f32x4 z4 = {0.f, 0.f, 0.f, 0.f};
    f32x4 accO[2][2], accSum[2];
    accO[0][0] = z4; accO[0][1] = z4; accO[1][0] = z4; accO[1][1] = z4;
    accSum[0] = z4; accSum[1] = z4;
    float m_i[2] = {-1e30f, -1e30f};

    const char* K0s = smem;          const char* V0s = smem + 12288;
    const char* K1s = smem + 4096;   const char* V1s = smem + 16384;
    const char* K2s = smem + 8192;   const char* V2s = smem + 20480;

    auto body = [&](const char* Kl, const char* Vt, char* Kn, char* Vn, int st) {
        // own-wave oldest pair (this tile's K,V) landed; K_{t+1},V_{t+1} may fly on
        if (st < 31) asm volatile("s_waitcnt vmcnt(2)" ::: "memory");
        else         asm volatile("s_waitcnt vmcnt(0)" ::: "memory");
        __builtin_amdgcn_s_barrier();   // all waves' chunks of tile t are in LDS

        if (st < 30) {                  // issue tile t+2 into slot (t+2)%3
            gl_lds16(kp + (size_t)ln * 8, Kn + wid * 1024);
            gl_lds16(vp + (size_t)ln * 8, Vn + wid * 1024);
            kp += 512;
            vp += 2048;
        }

        // S^T: A = K (m=s), B = Qscaled (n=q); already in exp2 units
        half8_t ak[4];
        #pragma unroll
        for (int mt = 0; mt < 4; ++mt)
            ak[mt] = *(const half8_t*)(Kl + quad * 1024 + (mt * 16 + l15) * 16);
        f32x4 accS[2][4];
        __builtin_amdgcn_s_setprio(1);
        #pragma unroll
        for (int i = 0; i < 2; ++i)
            #pragma unroll
            for (int mt = 0; mt < 4; ++mt)
                accS[i][mt] = __builtin_amdgcn_mfma_f32_16x16x32_f16(ak[mt], aq[i], z4, 0, 0, 0);
        __builtin_amdgcn_s_setprio(0);

        // per-q max (lane col l15): max3-fusable nesting, then quad-reduce shfl
        float mn[2];
        bool up = false;
        #pragma unroll
        for (int i = 0; i < 2; ++i) {
            float xm = fmaxf(fmaxf(accS[i][0][0], accS[i][0][1]), accS[i][0][2]);
            xm = fmaxf(fmaxf(xm, accS[i][0][3]), accS[i][1][0]);
            xm = fmaxf(fmaxf(xm, accS[i][1][1]), accS[i][1][2]);
            xm = fmaxf(fmaxf(xm, accS[i][1][3]), accS[i][2][0]);
            xm = fmaxf(fmaxf(xm, accS[i][2][1]), accS[i][2][2]);
            xm = fmaxf(fmaxf(xm, accS[i][2][3]), accS[i][3][0]);
            xm = fmaxf(fmaxf(xm, accS[i][3][1]), accS[i][3][2]);
            xm = fmaxf(xm, accS[i][3][3]);
            xm = fmaxf(xm, __shfl_xor(xm, 16));
            xm = fmaxf(xm, __shfl_xor(xm, 32));
            up = up || (xm > m_i[i] + 8.f);   // defer-max: P <= 2^8 safe in f16
            mn[i] = fmaxf(m_i[i], xm);
        }
        if (__ballot(up)) {   // wave-uniform rescale, only on real max growth
            #pragma unroll
            for (int i = 0; i < 2; ++i) {
                float alpha = __builtin_amdgcn_exp2f(m_i[i] - mn[i]);
                #pragma unroll
                for (int dt = 0; dt < 2; ++dt)
                    #pragma unroll
                    for (int r = 0; r < 4; ++r) accO[i][dt][r] *= alpha;
                #pragma unroll
                for (int r = 0; r < 4; ++r) accSum[i][r] *= alpha;
                m_i[i] = mn[i];
            }
        }

        // exp2 + packed P store (swizzled chunks: bank-uniform b64 writes)
        #pragma unroll
        for (int i = 0; i < 2; ++i) {
            #pragma unroll
            for (int mt = 0; mt < 4; ++mt) {
                float p0 = __builtin_amdgcn_exp2f(accS[i][mt][0] - m_i[i]);
                float p1 = __builtin_amdgcn_exp2f(accS[i][mt][1] - m_i[i]);
                float p2 = __builtin_amdgcn_exp2f(accS[i][mt][2] - m_i[i]);
                float p3 = __builtin_amdgcn_exp2f(accS[i][mt][3] - m_i[i]);
                int ch = (mt * 2 + (quad >> 1)) ^ l8;
                *(half4_t*)(Pw + (i * 16 + l15) * 128 + ch * 16 + (quad & 1) * 8) =
                    pack4(p0, p1, p2, p3);
            }
        }

        // O^T += V^T·P^T and rowsum += 1^T·P^T (ones-frag MFMA)
        #pragma unroll
        for (int kt = 0; kt < 2; ++kt) {
            half8_t av[2], bp[2];
            #pragma unroll
            for (int dt = 0; dt < 2; ++dt) {
                int d = dt * 16 + l15;
                int cp = (kt * 4 + quad) ^ (l15 & 7);
                av[dt] = *(const half8_t*)(Vt + d * 128 + cp * 16);
            }
            #pragma unroll
            for (int i = 0; i < 2; ++i)
                bp[i] = *(const half8_t*)(Pw + (i * 16 + l15) * 128 +
                                          (((kt * 4 + quad) ^ l8) * 16));
            __builtin_amdgcn_s_setprio(1);
            #pragma unroll
            for (int i = 0; i < 2; ++i) {
                #pragma unroll
                for (int dt = 0; dt < 2; ++dt)
                    accO[i][dt] = __builtin_amdgcn_mfma_f32_16x16x32_f16(av[dt], bp[i], accO[i][dt], 0, 0, 0);
                accSum[i] = __builtin_amdgcn_mfma_f32_16x16x32_f16(onesf, bp[i], accSum[i], 0, 0, 0);
            }
            __builtin_amdgcn_s_setprio(0);
        }
        // no bottom barrier: top-of-next-body wait+barrier covers reuse
    };

    #pragma unroll 1
    for (int tt = 0; tt < 10; ++tt) {
        body(K0s, V0s, (char*)K2s, (char*)V2s, tt * 3);
        body(K1s, V1s, (char*)K0s, (char*)V0s, tt * 3 + 1);
        body(K2s, V2s, (char*)K1s, (char*)V1s, tt * 3 + 2);
    }
    body(K0s, V0s, (char*)K2s, (char*)V2s, 30);
    body(K1s, V1s, (char*)K0s, (char*)V0s, 31);

    // epilogue: l_i lives in accSum[i][0] on quad-0 lanes (C row 0); broadcast.
    // normalize, transpose via wave-private LDS (32 rows x 80 B), coalesced store.
    #pragma unroll
    for (int i = 0; i < 2; ++i) {
        float li = __shfl(accSum[i][0], l15);
        float inv = 1.f / li;
        #pragma unroll
        for (int dt = 0; dt < 2; ++dt)
            *(half4_t*)(Pw + (i * 16 + l15) * 80 + (dt * 16 + quad * 4) * 2) =
                pack4(accO[i][dt][0] * inv, accO[i][dt][1] * inv,
                      accO[i][dt][2] * inv, accO[i][dt][3] * inv);
    }
    int q2 = ln >> 1, hf = ln & 1;
    half8_t o0 = *(const half8_t*)(Pw + q2 * 80 + hf * 32);
    half8_t o1 = *(const half8_t*)(Pw + q2 * 80 + hf * 32 + 16);
    size_t rowe = ((size_t)(n * 2048 + q0 + wid * 32 + q2)) * 512 + h * 32 + hf * 16;
    *(half8_t*)(Og + rowe) = o0;
    *(half8_t*)(Og + rowe + 8) = o1;
}

// ---------------------------------------------------------------- out-projection
// Out = O @ W2^T + b ; O f16 [n][l][512] (rows m = n*2048+l), Out f32 rows l*4+n.
// R10 K-loop: M-tile 64, grid (128,4), triple-buffer + counted vmcnt.
// R14: unroll-by-3 slot pointers. R11 epilogue: LDS re-stage Ef[64][132] f32,
// 512B contiguous output runs.
__global__ __launch_bounds__(256) void k_outproj(
    const f16* __restrict__ A, const f16* __restrict__ W2,
    const float* __restrict__ bias, float* __restrict__ Out)
{
    __shared__ __align__(16) char pool[36864];   // 3 slots x (A 4KB + B 8KB); Ef 33,792B aliases

    const int tid = threadIdx.x;
    const int m0 = blockIdx.x * 64;
    const int f0 = blockIdx.y * 128;
    const int wid = tid >> 6, ln = tid & 63, l15 = ln & 15, quad = ln >> 4;
    const int wm = wid >> 1, wn = wid & 1;
    const int srow = ln >> 2, sco = (ln & 3) * 8;

    f16* A0 = (f16*)(pool);          f16* B0 = (f16*)(pool + 4096);
    f16* A1 = (f16*)(pool + 12288);  f16* B1 = (f16*)(pool + 16384);
    f16* A2 = (f16*)(pool + 24576);  f16* B2 = (f16*)(pool + 28672);

    f32x4 z4 = {0.f, 0.f, 0.f, 0.f};
    f32x4 acc[2][4];
    #pragma unroll
    for (int i = 0; i < 2; ++i)
        #pragma unroll
        for (int j = 0; j < 4; ++j) acc[i][j] = z4;

    // per-tile staging: 3 gl_lds16 per wave (1 for A 16-row chunk, 2 for B)
    auto issue = [&](int kt, f16* As, f16* Bs) {
        const int k0 = kt * 32;
        int arow = wid * 16 + srow;
        gl_lds16(A + (size_t)(m0 + arow) * 512 + k0 + sco,
                 As + wid * 512);
        #pragma unroll
        for (int i = 0; i < 2; ++i) {
            int brow = wid * 32 + i * 16 + srow;
            gl_lds16(W2 + (size_t)(f0 + brow) * 512 + k0 + sco,
                     Bs + (wid * 32 + i * 16) * 32);
        }
    };
    issue(0, A0, B0);
    issue(1, A1, B1);

    auto bodyk = [&](int kt, const f16* As, const f16* Bs, f16* Ans, f16* Bns) {
        if (kt < 15) asm volatile("s_waitcnt vmcnt(3)" ::: "memory");
        else         asm volatile("s_waitcnt vmcnt(0)" ::: "memory");
        __builtin_amdgcn_s_barrier();

        if (kt < 14) issue(kt + 2, Ans, Bns);

        half8_t a[2], b[4];
        #pragma unroll
        for (int i = 0; i < 2; ++i)
            a[i] = *(const half8_t*)(As + (wm * 32 + i * 16 + l15) * 32 + quad * 8);
        #pragma unroll
        for (int j = 0; j < 4; ++j)
            b[j] = *(const half8_t*)(Bs + (wn * 64 + j * 16 + l15) * 32 + quad * 8);
        __builtin_amdgcn_s_setprio(1);
        #pragma unroll
        for (int i = 0; i < 2; ++i)
            #pragma unroll
            for (int j = 0; j < 4; ++j)
                acc[i][j] = __builtin_amdgcn_mfma_f32_16x16x32_f16(b[j], a[i], acc[i][j], 0, 0, 0);
        __builtin_amdgcn_s_setprio(0);
    };

    #pragma unroll 1
    for (int tt = 0; tt < 5; ++tt) {
        bodyk(tt * 3,     A0, B0, A2, B2);
        bodyk(tt * 3 + 1, A1, B1, A0, B0);
        bodyk(tt * 3 + 2, A2, B2, A1, B1);
    }
    bodyk(15, A0, B0, A2, B2);

    // ---- epilogue: LDS re-stage for coalesced output ----
    __syncthreads();
    float* Ef = (float*)pool;              // [mloc 64][132] f32, pad 4

    #pragma unroll
    for (int j = 0; j < 4; ++j) {
        int floc0 = wn * 64 + j * 16 + quad * 4;
        float4 bs4 = *(const float4*)(bias + f0 + floc0);
        #pragma unroll
        for (int i = 0; i < 2; ++i) {
            int mloc = wm * 32 + i * 16 + l15;
            float4 o;
            o.x = acc[i][j][0] + bs4.x;
            o.y = acc[i][j][1] + bs4.y;
            o.z = acc[i][j][2] + bs4.z;
            o.w = acc[i][j][3] + bs4.w;
            *(float4*)(Ef + mloc * 132 + floc0) = o;
        }
    }
    __syncthreads();

    // 8 half-waves x 8 passes: each half-wave writes one row's 128 floats (512B run)
    {
        int hw = tid >> 5, lane32 = tid & 31;
        #pragma unroll
        for (int it = 0; it < 8; ++it) {
            int row = it * 8 + hw;
            float4 v = *(const float4*)(Ef + row * 132 + lane32 * 4);
            int rm = m0 + row;
            int orow = (rm & 2047) * 4 + (rm >> 11);
            *(float4*)(Out + (size_t)orow * 512 + f0 + lane32 * 4) = v;
        }
    }
}

// ---------------------------------------------------------------- launch
extern "C" void kernel_launch(void* const* d_in, const int* in_sizes, int n_in,
                              void* d_out, int out_size, void* d_ws, size_t ws_size,
                              hipStream_t stream) {
    const float* query   = (const float*)d_in[0];
    const float* key_in  = (const float*)d_in[1];
    const float* value   = (const float*)d_in[2];
    const float* scaling = (const float*)d_in[3];
    const float* ipw     = (const float*)d_in[4];
    const float* ipb     = (const float*)d_in[5];
    const float* pnw     = (const float*)d_in[6];
    const float* pnb     = (const float*)d_in[7];
    const float* opw     = (const float*)d_in[8];
    const float* opb     = (const float*)d_in[9];
    float* out = (float*)d_out;

    // workspace (f16 element offsets):
    //   Qg 0 / Kg 4,194,304 / Vtg 8,388,608 (each 4,194,304)
    //   W1 12,582,912 (786,432) / W2 13,369,344 (262,144)
    //   Xh 13,631,488 (12,582,912; dead after k_inproj) ; Og aliases Xh head
    // total: 52,428,800 bytes
    f16* Qg  = (f16*)d_ws;
    f16* Kg  = Qg + (size_t)4194304;
    f16* Vtg = Qg + (size_t)8388608;
    f16* W1  = Qg + (size_t)12582912;
    f16* W2  = Qg + (size_t)13369344;
    f16* Xh  = Qg + (size_t)13631488;
    f16* Og  = Xh;   // alias (Xh consumed before k_flash writes Og)

    k_cast<<<3328, 256, 0, stream>>>(ipw, opw, query, key_in, value, W1, W2, Xh);
    k_inproj<<<768, 256, 0, stream>>>(Xh, W1, ipb, scaling, pnw, pnb, Qg, Kg, Vtg);
    k_flash<<<dim3(64, 16), 256, 0, stream>>>(Qg, Kg, Vtg, Og);
    k_outproj<<<dim3(128, 4), 256, 0, stream>>>(Og, W2, opb, out);
}

// Round 9
// 203.884 us; speedup vs baseline: 1.0433x; 1.0433x over previous
//
#include <hip/hip_runtime.h>
#include <cstdint>

// Problem constants
#define LN_EPS 1e-5f

typedef _Float16 f16;
typedef _Float16 half4_t __attribute__((ext_vector_type(4)));
typedef _Float16 half8_t __attribute__((ext_vector_type(8)));
typedef __fp16 fp16v2 __attribute__((ext_vector_type(2)));
typedef float f32x4 __attribute__((ext_vector_type(4)));

// async global->LDS, 16B per lane; LDS dest = wave-uniform base + lane*16
__device__ __forceinline__ void gl_lds16(const void* g, void* l) {
    __builtin_amdgcn_global_load_lds(
        (__attribute__((address_space(1))) void*)(uintptr_t)g,
        (__attribute__((address_space(3))) void*)(uint32_t)(uintptr_t)l,
        16, 0, 0);
}

// pack 4 floats -> 4 f16 via v_cvt_pkrtz
__device__ __forceinline__ half4_t pack4(float a, float b, float c, float d) {
    fp16v2 lo = __builtin_amdgcn_cvt_pkrtz(a, b);
    fp16v2 hi = __builtin_amdgcn_cvt_pkrtz(c, d);
    half4_t r;
    r[0] = (f16)lo[0]; r[1] = (f16)lo[1]; r[2] = (f16)hi[0]; r[3] = (f16)hi[1];
    return r;
}

// ---------------------------------------------------------------- cast weights + inputs
// W1 (1536x512), W2 (512x512), and X = [query|key_in|value] (3 x 8192x512) -> f16.
// R11: grid-stride (4 reps/thread) -> 3328 blocks.
__global__ void k_cast(const float* __restrict__ W1f, const float* __restrict__ W2f,
                       const float* __restrict__ Xq, const float* __restrict__ Xk,
                       const float* __restrict__ Xv,
                       f16* __restrict__ W1h, f16* __restrict__ W2h,
                       f16* __restrict__ Xh) {
    int t0 = blockIdx.x * blockDim.x + threadIdx.x;   // 3328*256 = 851,968 threads
    #pragma unroll
    for (int rep = 0; rep < 4; ++rep) {
        int t = t0 + rep * 851968;                    // 4 reps = 3,407,872 float4
        const float4* src;
        half4_t* dst;
        int idx;
        if (t < 196608)      { src = (const float4*)W1f; dst = (half4_t*)W1h; idx = t; }
        else if (t < 262144) { src = (const float4*)W2f; dst = (half4_t*)W2h; idx = t - 196608; }
        else {
            int u = t - 262144;               // 0 .. 3,145,727
            int s = u >> 20;                  // input selector (2^20 float4 per input)
            idx = u & 1048575;
            src = (s == 0) ? (const float4*)Xq : ((s == 1) ? (const float4*)Xk : (const float4*)Xv);
            dst = (half4_t*)(Xh + (size_t)s * 4194304);
        }
        float4 v = src[idx];
        dst[idx] = pack4(v.x, v.y, v.z, v.w);
    }
}

// ---------------------------------------------------------------- in-projection (+ fused LayerNorm for K,V; V written transposed)
// R7-measured version (slot-indexed K-loop; unroll-by-3 regressed this kernel in R8).
// C = X @ W^T + b ; X f16 (per-section 8192x512), W f16.
// Triple-buffered LDS + counted vmcnt(4) + raw s_barrier. Flat grid 768, XCD
// remap. Epilogue: fused Q-scale / LN; K chunk-major; V transposed to Vtg.
__global__ __launch_bounds__(256) void k_inproj(
    const f16* __restrict__ Xh, const f16* __restrict__ W1,
    const float* __restrict__ bias, const float* __restrict__ scaling,
    const float* __restrict__ pnw, const float* __restrict__ pnb,
    f16* __restrict__ Qg, f16* __restrict__ Kg, f16* __restrict__ Vtg)
{
    __shared__ __align__(16) char pool[49152];   // 3 slots x (A 8KB + B 8KB); Ep 32KB aliases

    const int tid = threadIdx.x;
    const int bid = blockIdx.x;                  // 768 blocks
    const int jj = bid >> 3;
    const int m0 = ((bid & 7) * 8 + (jj & 7)) * 128;   // m-block [0,64)*128
    const int f0 = (jj >> 3) * 128;                    // f-block [0,12)*128
    const int sec = f0 >> 9;
    const f16* X = Xh + (size_t)sec * 4194304;
    f16* Ob = (sec == 0) ? Qg : Kg;              // sec==2 uses Vtg path

    const int wid = tid >> 6, ln = tid & 63, l15 = ln & 15, quad = ln >> 4;
    const int wm = wid >> 1, wn = wid & 1;
    const int srow = ln >> 2, sco = (ln & 3) * 8;

    f32x4 z4 = {0.f, 0.f, 0.f, 0.f};
    f32x4 acc[4][4];
    #pragma unroll
    for (int i = 0; i < 4; ++i)
        #pragma unroll
        for (int j = 0; j < 4; ++j) acc[i][j] = z4;

    // per-tile staging: 4 gl_lds16 per wave (2 for B, 2 for A)
    auto issue = [&](int kt, int slot) {
        const int k0 = kt * 32;
        f16* As = (f16*)(pool + slot * 16384);
        f16* Bs = (f16*)(pool + slot * 16384 + 8192);
        #pragma unroll
        for (int i = 0; i < 2; ++i) {
            int row = wid * 32 + i * 16 + srow;
            gl_lds16(W1 + (size_t)(f0 + row) * 512 + k0 + sco,
                     Bs + (wid * 32 + i * 16) * 32);
            gl_lds16(X + (size_t)(m0 + row) * 512 + k0 + sco,
                     As + (wid * 32 + i * 16) * 32);
        }
    };
    issue(0, 0);
    issue(1, 1);

    int slot = 0;
    for (int kt = 0; kt < 16; ++kt) {
        if (kt < 15) asm volatile("s_waitcnt vmcnt(4)" ::: "memory");
        else         asm volatile("s_waitcnt vmcnt(0)" ::: "memory");
        __builtin_amdgcn_s_barrier();

        if (kt < 14) {
            int nb = slot + 2; if (nb >= 3) nb -= 3;
            issue(kt + 2, nb);
        }

        const f16* As = (const f16*)(pool + slot * 16384);
        const f16* Bs = (const f16*)(pool + slot * 16384 + 8192);
        half8_t a[4], b[4];
        #pragma unroll
        for (int i = 0; i < 4; ++i)
            a[i] = *(const half8_t*)(As + (wm * 64 + i * 16 + l15) * 32 + quad * 8);
        #pragma unroll
        for (int j = 0; j < 4; ++j)
            b[j] = *(const half8_t*)(Bs + (wn * 64 + j * 16 + l15) * 32 + quad * 8);
        __builtin_amdgcn_s_setprio(1);
        #pragma unroll
        for (int i = 0; i < 4; ++i)
            #pragma unroll
            for (int j = 0; j < 4; ++j)
                acc[i][j] = __builtin_amdgcn_mfma_f32_16x16x32_f16(b[j], a[i], acc[i][j], 0, 0, 0);
        __builtin_amdgcn_s_setprio(0);

        slot = slot + 1; if (slot == 3) slot = 0;
    }

    // ---- epilogue: bias (+Q-scale | +LN), LDS re-stage, coalesced output ----
    __syncthreads();                       // all waves done with staging slots
    f16* Ep = (f16*)pool;                  // [mloc 128][col 128], col fgrp XOR-swizzled

    // per-lane constants
    float sA = 0.f, sB = 0.f;              // Q scale for j<2 / j>=2 head
    float4 wA, wB, bA, bB;                 // LN params, d0 = (j&1)*16 + quad*4
    if (sec == 0) {
        int hbase = ((f0 & 511) >> 5) + wn * 2;
        sA = scaling[hbase] * 1.44269504f;
        sB = scaling[hbase + 1] * 1.44269504f;
    } else {
        wA = *(const float4*)(pnw + quad * 4);
        wB = *(const float4*)(pnw + 16 + quad * 4);
        bA = *(const float4*)(pnb + quad * 4);
        bB = *(const float4*)(pnb + 16 + quad * 4);
    }
    float4 bias4[4];
    #pragma unroll
    for (int j = 0; j < 4; ++j)
        bias4[j] = *(const float4*)(bias + f0 + wn * 64 + j * 16 + quad * 4);

    #pragma unroll
    for (int i = 0; i < 4; ++i) {
        float x[4][4];
        #pragma unroll
        for (int j = 0; j < 4; ++j) {
            x[j][0] = acc[i][j][0] + bias4[j].x;
            x[j][1] = acc[i][j][1] + bias4[j].y;
            x[j][2] = acc[i][j][2] + bias4[j].z;
            x[j][3] = acc[i][j][3] + bias4[j].w;
        }
        if (sec == 0) {
            #pragma unroll
            for (int j = 0; j < 4; ++j) {
                float sc = (j < 2) ? sA : sB;
                #pragma unroll
                for (int r = 0; r < 4; ++r) x[j][r] *= sc;
            }
        } else {
            // LN over the 32 features of each head: lane holds 8 (2 j x 4 r);
            // quad-reduce (shfl 16/32) completes the 32-feature sum.
            #pragma unroll
            for (int hp = 0; hp < 2; ++hp) {
                float s1 = 0.f, s2 = 0.f;
                #pragma unroll
                for (int jq = 0; jq < 2; ++jq) {
                    int j = hp * 2 + jq;
                    #pragma unroll
                    for (int r = 0; r < 4; ++r) { s1 += x[j][r]; s2 += x[j][r] * x[j][r]; }
                }
                s1 += __shfl_xor(s1, 16); s1 += __shfl_xor(s1, 32);
                s2 += __shfl_xor(s2, 16); s2 += __shfl_xor(s2, 32);
                float mu = s1 * (1.f / 32.f);
                float rs = rsqrtf(s2 * (1.f / 32.f) - mu * mu + LN_EPS);
                #pragma unroll
                for (int jq = 0; jq < 2; ++jq) {
                    int j = hp * 2 + jq;
                    const float4& wv = (j & 1) ? wB : wA;
                    const float4& bv = (j & 1) ? bB : bA;
                    x[j][0] = (x[j][0] - mu) * rs * wv.x + bv.x;
                    x[j][1] = (x[j][1] - mu) * rs * wv.y + bv.y;
                    x[j][2] = (x[j][2] - mu) * rs * wv.z + bv.z;
                    x[j][3] = (x[j][3] - mu) * rs * wv.w + bv.w;
                }
            }
        }
        int mloc = wm * 64 + i * 16 + l15;
        int key = (mloc >> 2) & 7;
        #pragma unroll
        for (int j = 0; j < 4; ++j) {
            int floc0 = wn * 64 + j * 16 + quad * 4;
            *(half4_t*)(Ep + mloc * 128 + (floc0 ^ (key << 3))) =
                pack4(x[j][0], x[j][1], x[j][2], x[j][3]);
        }
    }
    __syncthreads();

    if (sec < 2) {
        // read phase: thread owns fgrp (8 features); stores contiguous in l
        // (16 lanes x 16B = 256B runs). Q and K chunk-major T[g][c][len][8].
        int fgrp = (tid >> 6) * 4 + quad;       // 0..15
        int fs = (f0 & 511) + fgrp * 8;
        int hh = fs >> 5, cc = (fs >> 3) & 3;
        #pragma unroll
        for (int it = 0; it < 8; ++it) {
            int nb = it & 3, lblk = it >> 2;
            int L = lblk * 16 + l15;
            int mloc = nb + 4 * L;
            half8_t v = *(const half8_t*)(Ep + mloc * 128 + ((fgrp ^ (L & 7)) << 3));
            int gg = nb * 16 + hh;
            size_t l = (size_t)(m0 >> 2) + L;
            *(half8_t*)(Ob + (size_t)gg * 65536 + (size_t)cc * 16384 + l * 8) = v;
        }
    } else {
        // V: transpose-out straight to Vtg [g][seg][d=32][c'][8], c' = cs^(d&7).
        int seg = m0 >> 8;                      // (m0/128)>>1
        int csb = ((m0 >> 7) & 1) * 4;          // (m-block & 1)*4
        int hbase = (f0 & 511) >> 5;
        #pragma unroll
        for (int p = 0; p < 2; ++p) {
            int idx = tid * 2 + p;
            int g16 = idx >> 5, d = idx & 31;
            int nb = g16 >> 2, hhl = g16 & 3;
            int floc = hhl * 32 + d;
            size_t obase = (size_t)((nb * 16 + hbase + hhl) * 32 + seg) * 2048 + d * 64;
            #pragma unroll
            for (int cq = 0; cq < 4; ++cq) {
                half8_t hv;
                #pragma unroll
                for (int es = 0; es < 8; ++es) {
                    int mloc = nb + 4 * (cq * 8 + es);
                    hv[es] = Ep[mloc * 128 + (floc ^ (es << 3))];
                }
                int csx = (csb + cq) ^ (d & 7);
                *(half8_t*)(Vtg + obase + csx * 8) = hv;
            }
        }
    }
}

// ---------------------------------------------------------------- flash attention
// R14 (best measured: 73.2us). R8 schedule (counted vmcnt(2), one barrier/tile,
// 3-buf) with the tile loop unrolled by 3 so every LDS base is a compile-time
// slot pointer (LICM'd), plus max3-fusable fmax trees.
// LDS 40KB: K 3x4K @0 / V 3x4K @12288 / P 4x4K @24576 -> 4 blocks/CU.
__global__ __launch_bounds__(256, 4) void k_flash(
    const f16* __restrict__ Qg, const f16* __restrict__ Kg,
    const f16* __restrict__ Vtg, f16* __restrict__ Og)
{
    __shared__ __align__(16) char smem[40960];

    const int tid = threadIdx.x, wid = tid >> 6, ln = tid & 63;
    const int l15 = ln & 15, quad = ln >> 4, l8 = ln & 7;
    char* Pw = smem + 24576 + wid * 4096;
    const int g = blockIdx.x, h = g & 15, n = g >> 4;
    const int q0 = blockIdx.y * 128;

    // Q fragments: direct global->register. lane (l15,quad) holds
    // B[k = d = quad*8+j][n = q = wid*32 + i*16 + l15] (Qg chunk-major [g][c][l][8]).
    half8_t aq[2];
    #pragma unroll
    for (int i = 0; i < 2; ++i)
        aq[i] = *(const half8_t*)(Qg + (size_t)g * 65536 + (size_t)quad * 16384 +
                                  (size_t)(q0 + wid * 32 + i * 16 + l15) * 8);

    // prologue: issue K/V for tiles 0 and 1 (wave stages its c-chunk of each)
    const f16* kp = Kg + (size_t)g * 65536 + (size_t)wid * 16384;
    const f16* vp = Vtg + (size_t)(g * 32) * 2048 + wid * 512;
    gl_lds16(kp + (size_t)ln * 8, smem + wid * 1024);
    gl_lds16(vp + (size_t)ln * 8, smem + 12288 + wid * 1024);
    gl_lds16(kp + 512 + (size_t)ln * 8, smem + 4096 + wid * 1024);
    gl_lds16(vp + 2048 + (size_t)ln * 8, smem + 12288 + 4096 + wid * 1024);
    kp += 1024;   // now points at tile 2
    vp += 4096;

    // ones A-fragment: row m=0 is all 1 -> MFMA accumulates column sums of B
    half8_t onesf;
    {
        f16 o = (l15 == 0) ? (f16)1.0f : (f16)0.0f;
        #pragma unroll
        for (int j = 0; j < 8; ++j) onesf[j] = o;
    }

    f32x4 z4 = {0.f, 0.f, 0.f, 0.f};
    f32x4 accO[2][2], accSum[2];
    accO[0][0] = z4; accO[0][1] = z4; accO[1][0] = z4; accO[1][1] = z4;
    accSum[0] = z4; accSum[1] = z4;
    float m_i[2] = {-1e30f, -1e30f};

    const char* K0s = smem;          const char* V0s = smem + 12288;
    const char* K1s = smem + 4096;   const char* V1s = smem + 16384;
    const char* K2s = smem + 8192;   const char* V2s = smem + 20480;

    auto body = [&](const char* Kl, const char* Vt, char* Kn, char* Vn, int st) {
        // own-wave oldest pair (this tile's K,V) landed; K_{t+1},V_{t+1} may fly on
        if (st < 31) asm volatile("s_waitcnt vmcnt(2)" ::: "memory");
        else         asm volatile("s_waitcnt vmcnt(0)" ::: "memory");
        __builtin_amdgcn_s_barrier();   // all waves' chunks of tile t are in LDS

        if (st < 30) {                  // issue tile t+2 into slot (t+2)%3
            gl_lds16(kp + (size_t)ln * 8, Kn + wid * 1024);
            gl_lds16(vp + (size_t)ln * 8, Vn + wid * 1024);
            kp += 512;
            vp += 2048;
        }

        // S^T: A = K (m=s), B = Qscaled (n=q); already in exp2 units
        half8_t ak[4];
        #pragma unroll
        for (int mt = 0; mt < 4; ++mt)
            ak[mt] = *(const half8_t*)(Kl + quad * 1024 + (mt * 16 + l15) * 16);
        f32x4 accS[2][4];
        __builtin_amdgcn_s_setprio(1);
        #pragma unroll
        for (int i = 0; i < 2; ++i)
            #pragma unroll
            for (int mt = 0; mt < 4; ++mt)
                accS[i][mt] = __builtin_amdgcn_mfma_f32_16x16x32_f16(ak[mt], aq[i], z4, 0, 0, 0);
        __builtin_amdgcn_s_setprio(0);

        // per-q max (lane col l15): max3-fusable nesting, then quad-reduce shfl
        float mn[2];
        bool up = false;
        #pragma unroll
        for (int i = 0; i < 2; ++i) {
            float xm = fmaxf(fmaxf(accS[i][0][0], accS[i][0][1]), accS[i][0][2]);
            xm = fmaxf(fmaxf(xm, accS[i][0][3]), accS[i][1][0]);
            xm = fmaxf(fmaxf(xm, accS[i][1][1]), accS[i][1][2]);
            xm = fmaxf(fmaxf(xm, accS[i][1][3]), accS[i][2][0]);
            xm = fmaxf(fmaxf(xm, accS[i][2][1]), accS[i][2][2]);
            xm = fmaxf(fmaxf(xm, accS[i][2][3]), accS[i][3][0]);
            xm = fmaxf(fmaxf(xm, accS[i][3][1]), accS[i][3][2]);
            xm = fmaxf(xm, accS[i][3][3]);
            xm = fmaxf(xm, __shfl_xor(xm, 16));
            xm = fmaxf(xm, __shfl_xor(xm, 32));
            up = up || (xm > m_i[i] + 8.f);   // defer-max: P <= 2^8 safe in f16
            mn[i] = fmaxf(m_i[i], xm);
        }
        if (__ballot(up)) {   // wave-uniform rescale, only on real max growth
            #pragma unroll
            for (int i = 0; i < 2; ++i) {
                float alpha = __builtin_amdgcn_exp2f(m_i[i] - mn[i]);
                #pragma unroll
                for (int dt = 0; dt < 2; ++dt)
                    #pragma unroll
                    for (int r = 0; r < 4; ++r) accO[i][dt][r] *= alpha;
                #pragma unroll
                for (int r = 0; r < 4; ++r) accSum[i][r] *= alpha;
                m_i[i] = mn[i];
            }
        }

        // exp2 + packed P store (swizzled chunks: bank-uniform b64 writes)
        #pragma unroll
        for (int i = 0; i < 2; ++i) {
            #pragma unroll
            for (int mt = 0; mt < 4; ++mt) {
                float p0 = __builtin_amdgcn_exp2f(accS[i][mt][0] - m_i[i]);
                float p1 = __builtin_amdgcn_exp2f(accS[i][mt][1] - m_i[i]);
                float p2 = __builtin_amdgcn_exp2f(accS[i][mt][2] - m_i[i]);
                float p3 = __builtin_amdgcn_exp2f(accS[i][mt][3] - m_i[i]);
                int ch = (mt * 2 + (quad >> 1)) ^ l8;
                *(half4_t*)(Pw + (i * 16 + l15) * 128 + ch * 16 + (quad & 1) * 8) =
                    pack4(p0, p1, p2, p3);
            }
        }

        // O^T += V^T·P^T and rowsum += 1^T·P^T (ones-frag MFMA)
        #pragma unroll
        for (int kt = 0; kt < 2; ++kt) {
            half8_t av[2], bp[2];
            #pragma unroll
            for (int dt = 0; dt < 2; ++dt) {
                int d = dt * 16 + l15;
                int cp = (kt * 4 + quad) ^ (l15 & 7);
                av[dt] = *(const half8_t*)(Vt + d * 128 + cp * 16);
            }
            #pragma unroll
            for (int i = 0; i < 2; ++i)
                bp[i] = *(const half8_t*)(Pw + (i * 16 + l15) * 128 +
                                          (((kt * 4 + quad) ^ l8) * 16));
            __builtin_amdgcn_s_setprio(1);
            #pragma unroll
            for (int i = 0; i < 2; ++i) {
                #pragma unroll
                for (int dt = 0; dt < 2; ++dt)
                    accO[i][dt] = __builtin_amdgcn_mfma_f32_16x16x32_f16(av[dt], bp[i], accO[i][dt], 0, 0, 0);
                accSum[i] = __builtin_amdgcn_mfma_f32_16x16x32_f16(onesf, bp[i], accSum[i], 0, 0, 0);
            }
            __builtin_amdgcn_s_setprio(0);
        }
        // no bottom barrier: top-of-next-body wait+barrier covers reuse
    };

    #pragma unroll 1
    for (int tt = 0; tt < 10; ++tt) {
        body(K0s, V0s, (char*)K2s, (char*)V2s, tt * 3);
        body(K1s, V1s, (char*)K0s, (char*)V0s, tt * 3 + 1);
        body(K2s, V2s, (char*)K1s, (char*)V1s, tt * 3 + 2);
    }
    body(K0s, V0s, (char*)K2s, (char*)V2s, 30);
    body(K1s, V1s, (char*)K0s, (char*)V0s, 31);

    // epilogue: l_i lives in accSum[i][0] on quad-0 lanes (C row 0); broadcast.
    // normalize, transpose via wave-private LDS (32 rows x 80 B), coalesced store.
    #pragma unroll
    for (int i = 0; i < 2; ++i) {
        float li = __shfl(accSum[i][0], l15);
        float inv = 1.f / li;
        #pragma unroll
        for (int dt = 0; dt < 2; ++dt)
            *(half4_t*)(Pw + (i * 16 + l15) * 80 + (dt * 16 + quad * 4) * 2) =
                pack4(accO[i][dt][0] * inv, accO[i][dt][1] * inv,
                      accO[i][dt][2] * inv, accO[i][dt][3] * inv);
    }
    int q2 = ln >> 1, hf = ln & 1;
    half8_t o0 = *(const half8_t*)(Pw + q2 * 80 + hf * 32);
    half8_t o1 = *(const half8_t*)(Pw + q2 * 80 + hf * 32 + 16);
    size_t rowe = ((size_t)(n * 2048 + q0 + wid * 32 + q2)) * 512 + h * 32 + hf * 16;
    *(half8_t*)(Og + rowe) = o0;
    *(half8_t*)(Og + rowe + 8) = o1;
}

// ---------------------------------------------------------------- out-projection
// R7-measured version (slot-indexed K-loop; unroll-by-3 regressed this in R8).
// Out = O @ W2^T + b ; O f16 [n][l][512] (rows m = n*2048+l), Out f32 rows l*4+n.
// M-tile 64, grid (128,4), triple-buffer + counted vmcnt. Epilogue: LDS
// re-stage Ef[64][132] f32, 512B contiguous output runs.
__global__ __launch_bounds__(256) void k_outproj(
    const f16* __restrict__ A, const f16* __restrict__ W2,
    const float* __restrict__ bias, float* __restrict__ Out)
{
    __shared__ __align__(16) char pool[36864];   // 3 slots x (A 4KB + B 8KB); Ef 33,792B aliases

    const int tid = threadIdx.x;
    const int m0 = blockIdx.x * 64;
    const int f0 = blockIdx.y * 128;
    const int wid = tid >> 6, ln = tid & 63, l15 = ln & 15, quad = ln >> 4;
    const int wm = wid >> 1, wn = wid & 1;
    const int srow = ln >> 2, sco = (ln & 3) * 8;

    f32x4 z4 = {0.f, 0.f, 0.f, 0.f};
    f32x4 acc[2][4];
    #pragma unroll
    for (int i = 0; i < 2; ++i)
        #pragma unroll
        for (int j = 0; j < 4; ++j) acc[i][j] = z4;

    // per-tile staging: 3 gl_lds16 per wave (1 for A 16-row chunk, 2 for B)
    auto issue = [&](int kt, int slot) {
        const int k0 = kt * 32;
        f16* As = (f16*)(pool + slot * 12288);
        f16* Bs = (f16*)(pool + slot * 12288 + 4096);
        int arow = wid * 16 + srow;
        gl_lds16(A + (size_t)(m0 + arow) * 512 + k0 + sco,
                 As + wid * 512);
        #pragma unroll
        for (int i = 0; i < 2; ++i) {
            int brow = wid * 32 + i * 16 + srow;
            gl_lds16(W2 + (size_t)(f0 + brow) * 512 + k0 + sco,
                     Bs + (wid * 32 + i * 16) * 32);
        }
    };
    issue(0, 0);
    issue(1, 1);

    int slot = 0;
    for (int kt = 0; kt < 16; ++kt) {
        if (kt < 15) asm volatile("s_waitcnt vmcnt(3)" ::: "memory");
        else         asm volatile("s_waitcnt vmcnt(0)" ::: "memory");
        __builtin_amdgcn_s_barrier();

        if (kt < 14) {
            int nb = slot + 2; if (nb >= 3) nb -= 3;
            issue(kt + 2, nb);
        }

        const f16* As = (const f16*)(pool + slot * 12288);
        const f16* Bs = (const f16*)(pool + slot * 12288 + 4096);
        half8_t a[2], b[4];
        #pragma unroll
        for (int i = 0; i < 2; ++i)
            a[i] = *(const half8_t*)(As + (wm * 32 + i * 16 + l15) * 32 + quad * 8);
        #pragma unroll
        for (int j = 0; j < 4; ++j)
            b[j] = *(const half8_t*)(Bs + (wn * 64 + j * 16 + l15) * 32 + quad * 8);
        __builtin_amdgcn_s_setprio(1);
        #pragma unroll
        for (int i = 0; i < 2; ++i)
            #pragma unroll
            for (int j = 0; j < 4; ++j)
                acc[i][j] = __builtin_amdgcn_mfma_f32_16x16x32_f16(b[j], a[i], acc[i][j], 0, 0, 0);
        __builtin_amdgcn_s_setprio(0);

        slot = slot + 1; if (slot == 3) slot = 0;
    }

    // ---- epilogue: LDS re-stage for coalesced output ----
    __syncthreads();
    float* Ef = (float*)pool;              // [mloc 64][132] f32, pad 4

    #pragma unroll
    for (int j = 0; j < 4; ++j) {
        int floc0 = wn * 64 + j * 16 + quad * 4;
        float4 bs4 = *(const float4*)(bias + f0 + floc0);
        #pragma unroll
        for (int i = 0; i < 2; ++i) {
            int mloc = wm * 32 + i * 16 + l15;
            float4 o;
            o.x = acc[i][j][0] + bs4.x;
            o.y = acc[i][j][1] + bs4.y;
            o.z = acc[i][j][2] + bs4.z;
            o.w = acc[i][j][3] + bs4.w;
            *(float4*)(Ef + mloc * 132 + floc0) = o;
        }
    }
    __syncthreads();

    // 8 half-waves x 8 passes: each half-wave writes one row's 128 floats (512B run)
    {
        int hw = tid >> 5, lane32 = tid & 31;
        #pragma unroll
        for (int it = 0; it < 8; ++it) {
            int row = it * 8 + hw;
            float4 v = *(const float4*)(Ef + row * 132 + lane32 * 4);
            int rm = m0 + row;
            int orow = (rm & 2047) * 4 + (rm >> 11);
            *(float4*)(Out + (size_t)orow * 512 + f0 + lane32 * 4) = v;
        }
    }
}

// ---------------------------------------------------------------- launch
extern "C" void kernel_launch(void* const* d_in, const int* in_sizes, int n_in,
                              void* d_out, int out_size, void* d_ws, size_t ws_size,
                              hipStream_t stream) {
    const float* query   = (const float*)d_in[0];
    const float* key_in  = (const float*)d_in[1];
    const float* value   = (const float*)d_in[2];
    const float* scaling = (const float*)d_in[3];
    const float* ipw     = (const float*)d_in[4];
    const float* ipb     = (const float*)d_in[5];
    const float* pnw     = (const float*)d_in[6];
    const float* pnb     = (const float*)d_in[7];
    const float* opw     = (const float*)d_in[8];
    const float* opb     = (const float*)d_in[9];
    float* out = (float*)d_out;

    // workspace (f16 element offsets):
    //   Qg 0 / Kg 4,194,304 / Vtg 8,388,608 (each 4,194,304)
    //   W1 12,582,912 (786,432) / W2 13,369,344 (262,144)
    //   Xh 13,631,488 (12,582,912; dead after k_inproj) ; Og aliases Xh head
    // total: 52,428,800 bytes
    f16* Qg  = (f16*)d_ws;
    f16* Kg  = Qg + (size_t)4194304;
    f16* Vtg = Qg + (size_t)8388608;
    f16* W1  = Qg + (size_t)12582912;
    f16* W2  = Qg + (size_t)13369344;
    f16* Xh  = Qg + (size_t)13631488;
    f16* Og  = Xh;   // alias (Xh consumed before k_flash writes Og)

    k_cast<<<3328, 256, 0, stream>>>(ipw, opw, query, key_in, value, W1, W2, Xh);
    k_inproj<<<768, 256, 0, stream>>>(Xh, W1, ipb, scaling, pnw, pnb, Qg, Kg, Vtg);
    k_flash<<<dim3(64, 16), 256, 0, stream>>>(Qg, Kg, Vtg, Og);
    k_outproj<<<dim3(128, 4), 256, 0, stream>>>(Og, W2, opb, out);
}